// Round 1
// baseline (5068.698 us; speedup 1.0000x reference)
//
#include <hip/hip_runtime.h>
#include <hip/hip_bf16.h>
#include <math.h>

typedef __attribute__((ext_vector_type(8))) short bf16x8;
typedef __attribute__((ext_vector_type(4))) float f32x4;
typedef __attribute__((ext_vector_type(4))) unsigned short u16x4;

#define B_   16
#define C_   128
#define CHW_ 131072   // 128*32*32
#define K_   1152     // 128*9

__device__ __forceinline__ unsigned short f2bf(float f) {
  union { float f; unsigned int i; } v; v.f = f;
  unsigned int lsb = (v.i >> 16) & 1u;
  v.i += 0x7fffu + lsb;
  return (unsigned short)(v.i >> 16);
}

// ---- weight prep: W[O][I][3][3] f32 -> wbf[O][off*128+ci] bf16 (off=dh*3+dw)
__global__ void prep_weights(const float* __restrict__ W1, const float* __restrict__ W2,
                             unsigned short* __restrict__ w1bf, unsigned short* __restrict__ w2bf) {
  int j = blockIdx.x * 256 + threadIdx.x;
  if (j >= 2 * 147456) return;
  int which = j / 147456;
  int r = j - which * 147456;
  int co = r / 1152;
  int q  = r - co * 1152;
  int off = q >> 7;
  int ci  = q & 127;
  const float* src = which ? W2 : W1;
  unsigned short* dst = which ? w2bf : w1bf;
  dst[r] = f2bf(src[(co * 128 + ci) * 9 + off]);
}

// ---- init: y32 = y0 (NCHW f32); dout[:,t=0,...] = y0
__global__ void init_copy(const float* __restrict__ y0, float* __restrict__ y32,
                          float* __restrict__ dout) {
  int i = blockIdx.x * 256 + threadIdx.x;
  if (i >= B_ * CHW_) return;
  float v = y0[i];
  y32[i] = v;
  int b = i >> 17, chw = i & (CHW_ - 1);
  dout[b * 25 * CHW_ + chw] = v;
}

// ---- init: tmp_bf (NHWC bf16) = transpose(y0)
__global__ void init_transpose(const float* __restrict__ y0, unsigned short* __restrict__ tmp_bf) {
  __shared__ float t[32][33];
  int blk = blockIdx.x;          // 16 b * 4 co-tiles * 32 pix-tiles = 2048
  int b = blk >> 7;
  int rem = blk & 127;
  int co0 = (rem >> 5) * 32;
  int p0  = (rem & 31) * 32;
  int tx = threadIdx.x & 31, ty = threadIdx.x >> 5;
  #pragma unroll
  for (int k = 0; k < 4; k++) {
    int cl = ty + k * 8;
    t[cl][tx] = y0[b * CHW_ + (co0 + cl) * 1024 + p0 + tx];
  }
  __syncthreads();
  #pragma unroll
  for (int k = 0; k < 4; k++) {
    int pl = ty + k * 8;
    tmp_bf[(b * 1024 + p0 + pl) * 128 + co0 + tx] = f2bf(t[tx][pl]);
  }
}

// ---- fused conv (+bias) kernel, implicit GEMM via MFMA 16x16x32 bf16.
// STAGE 0: out_bf = tanh(conv(in, W1)+b1)           (the z buffer)
// STAGE 1: k1 = conv+b2; acc = y + dt/6 k1; tmp = y + dt/2 k1
// STAGE 2: k2;           acc += dt/3 k2;   tmp = y + dt/2 k2
// STAGE 3: k3;           acc += dt/3 k3;   tmp = y + dt   k3
// STAGE 4: k4; ynew = acc + dt/6 k4 -> y32, d_out[:,t], tmp
template<int STAGE>
__global__ __launch_bounds__(256)
void conv_kernel(const unsigned short* __restrict__ in_bf,   // NHWC bf16
                 const unsigned short* __restrict__ wbf,     // [128][1152] bf16
                 const float* __restrict__ bias,             // [128]
                 unsigned short* __restrict__ out_bf,        // NHWC bf16
                 float* __restrict__ y32,                    // NCHW f32
                 float* __restrict__ acc32,                  // NCHW f32
                 float* __restrict__ dout,                   // [B][25][C][H][W]
                 const float* __restrict__ tarr, int step)
{
  // input tile: 4 rows (r0-1..r0+2) x 34 cols (-1..32) x 128 ci, row stride 136
  __shared__ unsigned short tile[136 * 136];
  const int tid = threadIdx.x;
  const int b   = blockIdx.x >> 4;
  const int rt  = blockIdx.x & 15;
  const int r0  = rt * 2;

  // stage input tile (zero-padded halo), 16B chunks, fully coalesced
  for (int chunk = tid; chunk < 136 * 16; chunk += 256) {
    int pix = chunk >> 4;
    int oct = chunk & 15;
    int tr = pix / 34, tc = pix - tr * 34;
    int gr = r0 - 1 + tr, gc = tc - 1;
    bf16x8 v = {0, 0, 0, 0, 0, 0, 0, 0};
    if ((unsigned)gr < 32u && (unsigned)gc < 32u)
      v = *(const bf16x8*)(in_bf + ((b * 32 + gr) * 32 + gc) * 128 + oct * 8);
    *(bf16x8*)(tile + pix * 136 + oct * 8) = v;
  }
  __syncthreads();

  const int lane = tid & 63;
  const int wave = tid >> 6;
  const int wm = wave >> 1;      // co half (0..1)
  const int wn = wave & 1;       // output row within tile (0..1)
  const int lhi = lane >> 4;     // 0..3  (K octet / D row group)
  const int llo = lane & 15;     // A: co row, B: sp col, D: col

  f32x4 acc[4][2];
  #pragma unroll
  for (int i = 0; i < 4; i++)
    #pragma unroll
    for (int j = 0; j < 2; j++)
      acc[i][j] = (f32x4){0.f, 0.f, 0.f, 0.f};

  const unsigned short* wbase = wbf + (wm * 64 + llo) * K_ + lhi * 8;

  for (int off = 0; off < 9; ++off) {
    const int dh = off / 3;
    const int dw = off - 3 * dh;
    const int prow = (wn + dh) * 34;
    #pragma unroll
    for (int kk = 0; kk < 4; ++kk) {
      const int ks  = off * 4 + kk;           // K step (32 wide)
      const int ci0 = kk * 32 + lhi * 8;
      bf16x8 bfr[2], afr[4];
      #pragma unroll
      for (int spt = 0; spt < 2; ++spt) {
        int pix = prow + spt * 16 + llo + dw;
        bfr[spt] = *(const bf16x8*)(tile + pix * 136 + ci0);
      }
      #pragma unroll
      for (int ct = 0; ct < 4; ++ct)
        afr[ct] = *(const bf16x8*)(wbase + ct * 16 * K_ + ks * 32);
      #pragma unroll
      for (int ct = 0; ct < 4; ++ct)
        #pragma unroll
        for (int spt = 0; spt < 2; ++spt)
          acc[ct][spt] = __builtin_amdgcn_mfma_f32_16x16x32_bf16(afr[ct], bfr[spt], acc[ct][spt], 0, 0, 0);
    }
  }

  float dt = 0.f;
  if constexpr (STAGE >= 1) dt = tarr[step + 1] - tarr[step];
  const float dt6 = dt * (1.f / 6.f), dt3 = dt * (1.f / 3.f), dth = dt * 0.5f;

  #pragma unroll
  for (int ct = 0; ct < 4; ++ct) {
    const int co0 = wm * 64 + ct * 16 + lhi * 4;
    #pragma unroll
    for (int spt = 0; spt < 2; ++spt) {
      const int c = spt * 16 + llo;
      const int r = r0 + wn;
      const int pnhwc = (b * 1024 + r * 32 + c) * 128 + co0;
      f32x4 a = acc[ct][spt];
      u16x4 pk;
      if constexpr (STAGE == 0) {
        #pragma unroll
        for (int reg = 0; reg < 4; ++reg) {
          float v = tanhf(a[reg] + bias[co0 + reg]);
          pk[reg] = f2bf(v);
        }
        *(u16x4*)(out_bf + pnhwc) = pk;
      } else {
        const int idx0 = b * CHW_ + co0 * 1024 + r * 32 + c;
        #pragma unroll
        for (int reg = 0; reg < 4; ++reg) {
          float kv = a[reg] + bias[co0 + reg];
          int id = idx0 + reg * 1024;
          float tv;
          if constexpr (STAGE == 1) {
            float yv = y32[id];
            acc32[id] = yv + dt6 * kv;
            tv = yv + dth * kv;
          } else if constexpr (STAGE == 2) {
            float yv = y32[id];
            acc32[id] += dt3 * kv;
            tv = yv + dth * kv;
          } else if constexpr (STAGE == 3) {
            float yv = y32[id];
            acc32[id] += dt3 * kv;
            tv = yv + dt * kv;
          } else {  // STAGE 4
            tv = acc32[id] + dt6 * kv;
            y32[id] = tv;
            dout[(b * 25 + step + 1) * CHW_ + co0 * 1024 + r * 32 + c + reg * 1024] = tv;
          }
          pk[reg] = f2bf(tv);
        }
        *(u16x4*)(out_bf + pnhwc) = pk;
      }
    }
  }
}

extern "C" void kernel_launch(void* const* d_in, const int* in_sizes, int n_in,
                              void* d_out, int out_size, void* d_ws, size_t ws_size,
                              hipStream_t stream) {
  const float* y0   = (const float*)d_in[0];
  const float* tarr = (const float*)d_in[1];
  const float* W1   = (const float*)d_in[2];
  const float* b1   = (const float*)d_in[3];
  const float* W2   = (const float*)d_in[4];
  const float* b2   = (const float*)d_in[5];
  float* dout = (float*)d_out;

  char* ws = (char*)d_ws;
  float* y32             = (float*)(ws);                          // 8 MB
  float* acc32           = (float*)(ws + (8u << 20));             // 8 MB
  unsigned short* tmp_bf = (unsigned short*)(ws + (16u << 20));   // 4 MB (NHWC)
  unsigned short* z_bf   = (unsigned short*)(ws + (20u << 20));   // 4 MB (NHWC)
  unsigned short* w1bf   = (unsigned short*)(ws + (24u << 20));   // 288 KB
  unsigned short* w2bf   = (unsigned short*)(ws + (24u << 20) + 294912);

  prep_weights<<<(2 * 147456 + 255) / 256, 256, 0, stream>>>(W1, W2, w1bf, w2bf);
  init_copy<<<(B_ * CHW_ + 255) / 256, 256, 0, stream>>>(y0, y32, dout);
  init_transpose<<<2048, 256, 0, stream>>>(y0, tmp_bf);

  for (int step = 0; step < 24; ++step) {
    conv_kernel<0><<<256, 256, 0, stream>>>(tmp_bf, w1bf, b1, z_bf, nullptr, nullptr, nullptr, tarr, step);
    conv_kernel<1><<<256, 256, 0, stream>>>(z_bf, w2bf, b2, tmp_bf, y32, acc32, dout, tarr, step);
    conv_kernel<0><<<256, 256, 0, stream>>>(tmp_bf, w1bf, b1, z_bf, nullptr, nullptr, nullptr, tarr, step);
    conv_kernel<2><<<256, 256, 0, stream>>>(z_bf, w2bf, b2, tmp_bf, y32, acc32, dout, tarr, step);
    conv_kernel<0><<<256, 256, 0, stream>>>(tmp_bf, w1bf, b1, z_bf, nullptr, nullptr, nullptr, tarr, step);
    conv_kernel<3><<<256, 256, 0, stream>>>(z_bf, w2bf, b2, tmp_bf, y32, acc32, dout, tarr, step);
    conv_kernel<0><<<256, 256, 0, stream>>>(tmp_bf, w1bf, b1, z_bf, nullptr, nullptr, nullptr, tarr, step);
    conv_kernel<4><<<256, 256, 0, stream>>>(z_bf, w2bf, b2, tmp_bf, y32, acc32, dout, tarr, step);
  }
}

// Round 2
// 3172.287 us; speedup vs baseline: 1.5978x; 1.5978x over previous
//
#include <hip/hip_runtime.h>
#include <hip/hip_bf16.h>
#include <math.h>

typedef __attribute__((ext_vector_type(8))) short bf16x8;
typedef __attribute__((ext_vector_type(4))) float f32x4;
typedef __attribute__((ext_vector_type(4))) unsigned short u16x4;

#define B_   16
#define C_   128
#define CHW_ 131072   // 128*32*32
#define K_   1152     // 128*9

__device__ __forceinline__ unsigned short f2bf(float f) {
  union { float f; unsigned int i; } v; v.f = f;
  unsigned int lsb = (v.i >> 16) & 1u;
  v.i += 0x7fffu + lsb;
  return (unsigned short)(v.i >> 16);
}

// ---- weight prep: W[O][I][3][3] f32 -> wpk[ks][co][ci&31] bf16, ks = off*4 + (ci>>5)
__global__ void prep_weights(const float* __restrict__ W1, const float* __restrict__ W2,
                             unsigned short* __restrict__ w1bf, unsigned short* __restrict__ w2bf) {
  int j = blockIdx.x * 256 + threadIdx.x;
  if (j >= 2 * 147456) return;
  int which = j / 147456;
  int r = j - which * 147456;
  int ks = r >> 12;
  int co = (r >> 5) & 127;
  int c5 = r & 31;
  int off = ks >> 2;
  int ci  = (ks & 3) * 32 + c5;
  const float* src = which ? W2 : W1;
  unsigned short* dst = which ? w2bf : w1bf;
  dst[r] = f2bf(src[(co * 128 + ci) * 9 + off]);
}

// ---- init: y32 = y0 (NCHW f32); dout[:,t=0,...] = y0
__global__ void init_copy(const float* __restrict__ y0, float* __restrict__ y32,
                          float* __restrict__ dout) {
  int i = blockIdx.x * 256 + threadIdx.x;
  if (i >= B_ * CHW_) return;
  float v = y0[i];
  y32[i] = v;
  int b = i >> 17, chw = i & (CHW_ - 1);
  dout[b * 25 * CHW_ + chw] = v;
}

// ---- init: tmp_bf (NHWC bf16) = transpose(y0)
__global__ void init_transpose(const float* __restrict__ y0, unsigned short* __restrict__ tmp_bf) {
  __shared__ float t[32][33];
  int blk = blockIdx.x;          // 16 b * 4 co-tiles * 32 pix-tiles = 2048
  int b = blk >> 7;
  int rem = blk & 127;
  int co0 = (rem >> 5) * 32;
  int p0  = (rem & 31) * 32;
  int tx = threadIdx.x & 31, ty = threadIdx.x >> 5;
  #pragma unroll
  for (int k = 0; k < 4; k++) {
    int cl = ty + k * 8;
    t[cl][tx] = y0[b * CHW_ + (co0 + cl) * 1024 + p0 + tx];
  }
  __syncthreads();
  #pragma unroll
  for (int k = 0; k < 4; k++) {
    int pl = ty + k * 8;
    tmp_bf[(b * 1024 + p0 + pl) * 128 + co0 + tx] = f2bf(t[tx][pl]);
  }
}

// ---- fused conv (+bias) kernel, implicit GEMM via MFMA 16x16x32 bf16.
// Block: 1 output row (32 px) x 64 co (co-half). Grid: 16b * 32rows * 2 halves = 1024.
// Wave (4/block): 16 co x 32 px  -> 2 accumulator tiles of 16x16.
// STAGE 0: out_bf = tanh(conv(in, W1)+b1)           (the z buffer)
// STAGE 1: k1 = conv+b2; acc = y + dt/6 k1; tmp = y + dt/2 k1
// STAGE 2: k2;           acc += dt/3 k2;   tmp = y + dt/2 k2
// STAGE 3: k3;           acc += dt/3 k3;   tmp = y + dt   k3
// STAGE 4: k4; ynew = acc + dt/6 k4 -> y32, d_out[:,t], tmp
template<int STAGE>
__global__ __launch_bounds__(256, 4)
void conv_kernel(const unsigned short* __restrict__ in_bf,   // NHWC bf16
                 const unsigned short* __restrict__ wpk,     // [36][128][32] bf16
                 const float* __restrict__ bias,             // [128]
                 unsigned short* __restrict__ out_bf,        // NHWC bf16
                 float* __restrict__ y32,                    // NCHW f32
                 float* __restrict__ acc32,                  // NCHW f32
                 float* __restrict__ dout,                   // [B][25][C][H][W]
                 const float* __restrict__ tarr, int step)
{
  // input tile: 3 rows (r0-1..r0+1) x 34 cols (-1..32) x 128 ci, row stride 136
  __shared__ unsigned short tile[102 * 136];
  const int tid = threadIdx.x;
  const int b   = blockIdx.x >> 6;
  const int rem = blockIdx.x & 63;
  const int r0  = rem >> 1;
  const int wmb = rem & 1;       // co half

  // stage input tile (zero-padded halo), 16B chunks, fully coalesced
  for (int chunk = tid; chunk < 102 * 16; chunk += 256) {
    int pix = chunk >> 4;
    int oct = chunk & 15;
    int tr = pix / 34, tc = pix - tr * 34;
    int gr = r0 - 1 + tr, gc = tc - 1;
    bf16x8 v = {0, 0, 0, 0, 0, 0, 0, 0};
    if ((unsigned)gr < 32u && (unsigned)gc < 32u)
      v = *(const bf16x8*)(in_bf + ((b * 32 + gr) * 32 + gc) * 128 + oct * 8);
    *(bf16x8*)(tile + pix * 136 + oct * 8) = v;
  }
  __syncthreads();

  const int lane = tid & 63;
  const int wave = tid >> 6;
  const int lhi = lane >> 4;     // 0..3  (K octet / D row group)
  const int llo = lane & 15;     // A: co row, B: sp col, D: col
  const int co0w = wmb * 64 + wave * 16;

  f32x4 acc[2];
  acc[0] = (f32x4){0.f, 0.f, 0.f, 0.f};
  acc[1] = (f32x4){0.f, 0.f, 0.f, 0.f};

  // A: wpk[(ks*128 + co0w + llo)*32 + lhi*8], fully coalesced 1KB/wave
  const unsigned short* abase = wpk + (co0w + llo) * 32 + lhi * 8;

  for (int off = 0; off < 9; ++off) {
    const int dh = off / 3;
    const int dw = off - 3 * dh;
    const int prow = dh * 34;
    #pragma unroll
    for (int kk = 0; kk < 4; ++kk) {
      const int ks = off * 4 + kk;           // K step (32 wide)
      bf16x8 afr = *(const bf16x8*)(abase + ks * 4096);
      #pragma unroll
      for (int spt = 0; spt < 2; ++spt) {
        int pix = prow + spt * 16 + llo + dw;
        bf16x8 bfr = *(const bf16x8*)(tile + pix * 136 + kk * 32 + lhi * 8);
        acc[spt] = __builtin_amdgcn_mfma_f32_16x16x32_bf16(afr, bfr, acc[spt], 0, 0, 0);
      }
    }
  }

  float dt = 0.f;
  if constexpr (STAGE >= 1) dt = tarr[step + 1] - tarr[step];
  const float dt6 = dt * (1.f / 6.f), dt3 = dt * (1.f / 3.f), dth = dt * 0.5f;

  const int co0 = co0w + lhi * 4;
  #pragma unroll
  for (int spt = 0; spt < 2; ++spt) {
    const int c = spt * 16 + llo;
    const int pnhwc = (b * 1024 + r0 * 32 + c) * 128 + co0;
    f32x4 a = acc[spt];
    u16x4 pk;
    if constexpr (STAGE == 0) {
      #pragma unroll
      for (int reg = 0; reg < 4; ++reg) {
        float v = tanhf(a[reg] + bias[co0 + reg]);
        pk[reg] = f2bf(v);
      }
      *(u16x4*)(out_bf + pnhwc) = pk;
    } else {
      const int idx0 = b * CHW_ + co0 * 1024 + r0 * 32 + c;
      #pragma unroll
      for (int reg = 0; reg < 4; ++reg) {
        float kv = a[reg] + bias[co0 + reg];
        int id = idx0 + reg * 1024;
        float tv;
        if constexpr (STAGE == 1) {
          float yv = y32[id];
          acc32[id] = yv + dt6 * kv;
          tv = yv + dth * kv;
        } else if constexpr (STAGE == 2) {
          float yv = y32[id];
          acc32[id] += dt3 * kv;
          tv = yv + dth * kv;
        } else if constexpr (STAGE == 3) {
          float yv = y32[id];
          acc32[id] += dt3 * kv;
          tv = yv + dt * kv;
        } else {  // STAGE 4
          tv = acc32[id] + dt6 * kv;
          y32[id] = tv;
          dout[(b * 25 + step + 1) * CHW_ + co0 * 1024 + r0 * 32 + c + reg * 1024] = tv;
        }
        pk[reg] = f2bf(tv);
      }
      *(u16x4*)(out_bf + pnhwc) = pk;
    }
  }
}

extern "C" void kernel_launch(void* const* d_in, const int* in_sizes, int n_in,
                              void* d_out, int out_size, void* d_ws, size_t ws_size,
                              hipStream_t stream) {
  const float* y0   = (const float*)d_in[0];
  const float* tarr = (const float*)d_in[1];
  const float* W1   = (const float*)d_in[2];
  const float* b1   = (const float*)d_in[3];
  const float* W2   = (const float*)d_in[4];
  const float* b2   = (const float*)d_in[5];
  float* dout = (float*)d_out;

  char* ws = (char*)d_ws;
  float* y32             = (float*)(ws);                          // 8 MB
  float* acc32           = (float*)(ws + (8u << 20));             // 8 MB
  unsigned short* tmp_bf = (unsigned short*)(ws + (16u << 20));   // 4 MB (NHWC)
  unsigned short* z_bf   = (unsigned short*)(ws + (20u << 20));   // 4 MB (NHWC)
  unsigned short* w1bf   = (unsigned short*)(ws + (24u << 20));   // 288 KB
  unsigned short* w2bf   = (unsigned short*)(ws + (24u << 20) + 294912);

  prep_weights<<<(2 * 147456 + 255) / 256, 256, 0, stream>>>(W1, W2, w1bf, w2bf);
  init_copy<<<(B_ * CHW_ + 255) / 256, 256, 0, stream>>>(y0, y32, dout);
  init_transpose<<<2048, 256, 0, stream>>>(y0, tmp_bf);

  for (int step = 0; step < 24; ++step) {
    conv_kernel<0><<<1024, 256, 0, stream>>>(tmp_bf, w1bf, b1, z_bf, nullptr, nullptr, nullptr, tarr, step);
    conv_kernel<1><<<1024, 256, 0, stream>>>(z_bf, w2bf, b2, tmp_bf, y32, acc32, dout, tarr, step);
    conv_kernel<0><<<1024, 256, 0, stream>>>(tmp_bf, w1bf, b1, z_bf, nullptr, nullptr, nullptr, tarr, step);
    conv_kernel<2><<<1024, 256, 0, stream>>>(z_bf, w2bf, b2, tmp_bf, y32, acc32, dout, tarr, step);
    conv_kernel<0><<<1024, 256, 0, stream>>>(tmp_bf, w1bf, b1, z_bf, nullptr, nullptr, nullptr, tarr, step);
    conv_kernel<3><<<1024, 256, 0, stream>>>(z_bf, w2bf, b2, tmp_bf, y32, acc32, dout, tarr, step);
    conv_kernel<0><<<1024, 256, 0, stream>>>(tmp_bf, w1bf, b1, z_bf, nullptr, nullptr, nullptr, tarr, step);
    conv_kernel<4><<<1024, 256, 0, stream>>>(z_bf, w2bf, b2, tmp_bf, y32, acc32, dout, tarr, step);
  }
}